// Round 1
// baseline (226.296 us; speedup 1.0000x reference)
//
#include <hip/hip_runtime.h>

#define N_TOK 256
#define CP    128
#define CHD   32
#define NH    4
#define NT    65536   // N_TOK*N_TOK
#define NCOL  528     // 512 (q|k|v|g) + 4 (b) + 12 pad

typedef short short8 __attribute__((ext_vector_type(8)));
typedef float f32x4  __attribute__((ext_vector_type(4)));

__device__ __forceinline__ short f2bf(float f) {
    unsigned u = __builtin_bit_cast(unsigned, f);
    u += 0x7fffu + ((u >> 16) & 1u);   // RTNE
    return (short)(u >> 16);
}
__device__ __forceinline__ float bf2f(short s) {
    unsigned u = ((unsigned)(unsigned short)s) << 16;
    return __builtin_bit_cast(float, u);
}

// ---------------------------------------------------------------- kernel 0
// Pack weights to bf16, n-major (WcatT[n][k], WoutT[n][k]) so B-fragments
// (lane: n = lane&15, k = quad*8+j) are contiguous 16B loads.
__global__ void pack_weights(const float* __restrict__ Wq, const float* __restrict__ Wk,
                             const float* __restrict__ Wv, const float* __restrict__ Wb,
                             const float* __restrict__ Wg, const float* __restrict__ Wout,
                             short* __restrict__ wcat, short* __restrict__ woutT) {
    int idx = blockIdx.x * 256 + threadIdx.x;
    if (idx < NCOL * CP) {
        int n = idx >> 7, k = idx & 127;
        float v = 0.f;
        if (n < 512) {
            const float* W = (n < 128) ? Wq : (n < 256) ? Wk : (n < 384) ? Wv : Wg;
            v = W[k * 128 + (n & 127)];
        } else if (n < 516) {
            v = Wb[k * 4 + (n - 512)];
        }
        wcat[n * CP + k] = f2bf(v);
    } else {
        int j = idx - NCOL * CP;
        if (j < 128 * 128) {
            int n = j >> 7, k = j & 127;
            woutT[n * 128 + k] = f2bf(Wout[k * 128 + n]);
        }
    }
}

// ---------------------------------------------------------------- kernel 1
// LayerNorm (fp32) + projections (bf16 MFMA).  64 rows/block, 4 waves.
// Outputs: qt/kt/vt/gt as [h][row][32] bf16, bt as [h][row] fp32.
__global__ __launch_bounds__(256)
void ln_proj(const float* __restrict__ pair, const float* __restrict__ gamma,
             const float* __restrict__ beta, const short* __restrict__ wcat,
             short* __restrict__ qt, short* __restrict__ kt,
             short* __restrict__ vt, short* __restrict__ gt,
             float* __restrict__ bt) {
    __shared__ short pn[64 * 136];           // pad 128->136: 2-way b128 reads
    const int tid = threadIdx.x;
    const int wv = tid >> 6, lane = tid & 63;
    const int quad = lane >> 4, l15 = lane & 15;
    const int r0 = blockIdx.x * 64;

    float ga0 = gamma[2 * lane], ga1 = gamma[2 * lane + 1];
    float be0 = beta[2 * lane],  be1 = beta[2 * lane + 1];

    #pragma unroll 4
    for (int rr = 0; rr < 16; ++rr) {
        int row = wv * 16 + rr;
        const float* src = pair + (size_t)(r0 + row) * CP + 2 * lane;
        float x0 = src[0], x1 = src[1];
        float s = x0 + x1;
        #pragma unroll
        for (int m = 32; m; m >>= 1) s += __shfl_xor(s, m);
        float mu = s * (1.f / 128.f);
        float d0 = x0 - mu, d1 = x1 - mu;
        float vs = d0 * d0 + d1 * d1;
        #pragma unroll
        for (int m = 32; m; m >>= 1) vs += __shfl_xor(vs, m);
        float rs = rsqrtf(vs * (1.f / 128.f) + 1e-5f);
        short y0 = f2bf(d0 * rs * ga0 + be0);
        short y1 = f2bf(d1 * rs * ga1 + be1);
        unsigned pk = ((unsigned)(unsigned short)y0) | (((unsigned)(unsigned short)y1) << 16);
        *(unsigned*)&pn[row * 136 + 2 * lane] = pk;
    }
    __syncthreads();

    short8 afrag[4];
    #pragma unroll
    for (int s = 0; s < 4; ++s)
        afrag[s] = *(const short8*)&pn[(wv * 16 + l15) * 136 + s * 32 + quad * 8];

    for (int ch = 0; ch < 33; ++ch) {
        int n = ch * 16 + l15;
        f32x4 acc = {0.f, 0.f, 0.f, 0.f};
        #pragma unroll
        for (int s = 0; s < 4; ++s) {
            short8 bfrag = *(const short8*)&wcat[(size_t)n * CP + s * 32 + quad * 8];
            acc = __builtin_amdgcn_mfma_f32_16x16x32_bf16(afrag[s], bfrag, acc, 0, 0, 0);
        }
        if (ch < 32) {
            int arr = n >> 7;                 // 0=q 1=k 2=v 3=g (chunk-uniform)
            int h = (n >> 5) & 3, c = n & 31;
            short* dst = (arr == 0) ? qt : (arr == 1) ? kt : (arr == 2) ? vt : gt;
            size_t base = (size_t)h * NT * CHD + c;
            #pragma unroll
            for (int r = 0; r < 4; ++r) {
                int gr = r0 + wv * 16 + quad * 4 + r;
                float val = acc[r];
                if (arr == 3) val = 1.f / (1.f + __expf(-val));   // sigmoid gate
                dst[base + (size_t)gr * CHD] = f2bf(val);
            }
        } else if (l15 < 4) {                 // chunk 32: pairwise bias b (fp32)
            int h = l15;
            #pragma unroll
            for (int r = 0; r < 4; ++r) {
                int gr = r0 + wv * 16 + quad * 4 + r;
                bt[h * NT + gr] = acc[r];
            }
        }
    }
}

// ---------------------------------------------------------------- kernel 2
// Attention per (i,h).  4 j-tiles of 64 rows; wave owns 16 rows.
// S strip (16x256) in 64 VGPRs; softmax in registers (width-16 shuffles);
// P through LDS (C-layout -> A-layout); PV with v transposed in LDS.
__global__ __launch_bounds__(256)
void attn(const short* __restrict__ qt, const short* __restrict__ kt,
          const short* __restrict__ vt, const short* __restrict__ gt,
          const float* __restrict__ bt, short* __restrict__ og) {
    __shared__ short vT[32 * 264];    // [c][key], pad 256->264
    __shared__ short pl[64 * 264];    // [j_local][key], per-wave 16-row strips
    const int tid = threadIdx.x;
    const int h = blockIdx.x >> 8, i = blockIdx.x & 255;   // same-h blocks adjacent: b slice stays in L2
    const int wv = tid >> 6, lane = tid & 63;
    const int quad = lane >> 4, l15 = lane & 15;

    const short* kbase = kt + ((size_t)h * NT + (size_t)i * 256) * CHD;
    const short* vbase = vt + ((size_t)h * NT + (size_t)i * 256) * CHD;
    const short* qbase = qt + ((size_t)h * NT + (size_t)i * 256) * CHD;
    const short* gbase = gt + ((size_t)h * NT + (size_t)i * 256) * CHD;
    const float* bbase = bt + (size_t)h * NT;

    // stage v transposed: coalesced 16B global loads, scattered b16 LDS writes
    for (int g = tid; g < 1024; g += 256) {
        int key = g >> 2, p = g & 3;
        short8 s = *(const short8*)(vbase + key * CHD + p * 8);
        #pragma unroll
        for (int cc = 0; cc < 8; ++cc)
            vT[(p * 8 + cc) * 264 + key] = s[cc];
    }
    __syncthreads();

    const float scale = 0.17677669529663687f;  // 1/sqrt(32)

    for (int jt = 0; jt < 4; ++jt) {
        int jbase = jt * 64 + wv * 16;
        // A-fragment: q rows, straight from global (1KB/wave, coalesced)
        short8 aq = *(const short8*)(qbase + (jbase + l15) * CHD + quad * 8);

        f32x4 sacc[16];
        #pragma unroll
        for (int t = 0; t < 16; ++t) {
            short8 bk = *(const short8*)(kbase + (t * 16 + l15) * CHD + quad * 8);
            f32x4 z = {0.f, 0.f, 0.f, 0.f};
            sacc[t] = __builtin_amdgcn_mfma_f32_16x16x32_bf16(aq, bk, z, 0, 0, 0);
        }
        // scale + pairwise bias (fp32, L2-resident)
        #pragma unroll
        for (int t = 0; t < 16; ++t)
            #pragma unroll
            for (int r = 0; r < 4; ++r) {
                int j = jbase + quad * 4 + r;
                sacc[t][r] = sacc[t][r] * scale + bbase[(size_t)j * 256 + t * 16 + l15];
            }
        // softmax over k (row j lives in reg r of the 16 lanes of this quad)
        float mx[4] = {-1e30f, -1e30f, -1e30f, -1e30f}, sm[4] = {0.f, 0.f, 0.f, 0.f};
        #pragma unroll
        for (int t = 0; t < 16; ++t)
            #pragma unroll
            for (int r = 0; r < 4; ++r) mx[r] = fmaxf(mx[r], sacc[t][r]);
        #pragma unroll
        for (int m = 1; m < 16; m <<= 1)
            #pragma unroll
            for (int r = 0; r < 4; ++r) mx[r] = fmaxf(mx[r], __shfl_xor(mx[r], m, 16));
        #pragma unroll
        for (int t = 0; t < 16; ++t)
            #pragma unroll
            for (int r = 0; r < 4; ++r) {
                float e = __expf(sacc[t][r] - mx[r]);
                sacc[t][r] = e;
                sm[r] += e;
            }
        #pragma unroll
        for (int m = 1; m < 16; m <<= 1)
            #pragma unroll
            for (int r = 0; r < 4; ++r) sm[r] += __shfl_xor(sm[r], m, 16);
        float inv[4];
        #pragma unroll
        for (int r = 0; r < 4; ++r) inv[r] = 1.f / sm[r];
        // P -> LDS (C-layout writes, A-layout reads)
        #pragma unroll
        for (int t = 0; t < 16; ++t)
            #pragma unroll
            for (int r = 0; r < 4; ++r)
                pl[(wv * 16 + quad * 4 + r) * 264 + t * 16 + l15] = f2bf(sacc[t][r] * inv[r]);
        __syncthreads();
        // PV
        f32x4 oacc[2];
        oacc[0] = f32x4{0.f, 0.f, 0.f, 0.f};
        oacc[1] = f32x4{0.f, 0.f, 0.f, 0.f};
        #pragma unroll
        for (int ks = 0; ks < 8; ++ks) {
            short8 ap = *(const short8*)&pl[(wv * 16 + l15) * 264 + ks * 32 + quad * 8];
            #pragma unroll
            for (int nt = 0; nt < 2; ++nt) {
                short8 bv = *(const short8*)&vT[(nt * 16 + l15) * 264 + ks * 32 + quad * 8];
                oacc[nt] = __builtin_amdgcn_mfma_f32_16x16x32_bf16(ap, bv, oacc[nt], 0, 0, 0);
            }
        }
        // gate + store og[row][h*32+c] bf16
        #pragma unroll
        for (int nt = 0; nt < 2; ++nt) {
            int c = nt * 16 + l15;
            #pragma unroll
            for (int r = 0; r < 4; ++r) {
                int j = jbase + quad * 4 + r;
                float gv = bf2f(gbase[(size_t)j * CHD + c]);
                float o = oacc[nt][r] * gv;
                og[((size_t)i * 256 + j) * CP + h * CHD + c] = f2bf(o);
            }
        }
        __syncthreads();
    }
}

// ---------------------------------------------------------------- kernel 3
// out = og[65536,128] @ Wout[128,128]  (bf16 MFMA, fp32 out)
__global__ __launch_bounds__(256)
void out_gemm(const short* __restrict__ og, const short* __restrict__ woutT,
              float* __restrict__ out) {
    __shared__ short al[64 * 136];
    const int tid = threadIdx.x;
    const int wv = tid >> 6, lane = tid & 63;
    const int quad = lane >> 4, l15 = lane & 15;
    const int r0 = blockIdx.x * 64;

    for (int g = tid; g < 1024; g += 256) {
        int row = g >> 4, p = g & 15;
        *(short8*)&al[row * 136 + p * 8] = *(const short8*)(og + (size_t)(r0 + row) * CP + p * 8);
    }
    __syncthreads();

    short8 af[4];
    #pragma unroll
    for (int s = 0; s < 4; ++s)
        af[s] = *(const short8*)&al[(wv * 16 + l15) * 136 + s * 32 + quad * 8];

    #pragma unroll
    for (int ch = 0; ch < 8; ++ch) {
        int n = ch * 16 + l15;
        f32x4 acc = {0.f, 0.f, 0.f, 0.f};
        #pragma unroll
        for (int s = 0; s < 4; ++s) {
            short8 bfrag = *(const short8*)&woutT[(size_t)n * 128 + s * 32 + quad * 8];
            acc = __builtin_amdgcn_mfma_f32_16x16x32_bf16(af[s], bfrag, acc, 0, 0, 0);
        }
        #pragma unroll
        for (int r = 0; r < 4; ++r)
            out[(size_t)(r0 + wv * 16 + quad * 4 + r) * CP + n] = acc[r];
    }
}

// ---------------------------------------------------------------- launch
extern "C" void kernel_launch(void* const* d_in, const int* in_sizes, int n_in,
                              void* d_out, int out_size, void* d_ws, size_t ws_size,
                              hipStream_t stream) {
    (void)in_sizes; (void)n_in; (void)out_size; (void)ws_size;
    const float* pair  = (const float*)d_in[0];
    const float* gamma = (const float*)d_in[1];
    const float* beta  = (const float*)d_in[2];
    const float* Wq    = (const float*)d_in[3];
    const float* Wk    = (const float*)d_in[4];
    const float* Wv    = (const float*)d_in[5];
    const float* Wb    = (const float*)d_in[6];
    const float* Wg    = (const float*)d_in[7];
    const float* Wout  = (const float*)d_in[8];
    float* out = (float*)d_out;

    char* ws = (char*)d_ws;
    const size_t SZ_QKVG = (size_t)NH * NT * CHD * 2;           // 16 MB each
    short* wcat  = (short*)(ws);                                 // 528*128*2 = 135168
    short* woutT = (short*)(ws + 135168);                        // 32768
    short* qt    = (short*)(ws + 167936);
    short* kt    = (short*)(ws + 167936 + SZ_QKVG);
    short* vt    = (short*)(ws + 167936 + 2 * SZ_QKVG);
    short* gt    = (short*)(ws + 167936 + 3 * SZ_QKVG);
    float* bt    = (float*)(ws + 167936 + 4 * SZ_QKVG);          // NH*NT*4 = 1 MB
    short* og    = (short*)(ws + 167936 + 4 * SZ_QKVG + (size_t)NH * NT * 4);

    hipLaunchKernelGGL(pack_weights, dim3(328), dim3(256), 0, stream,
                       Wq, Wk, Wv, Wb, Wg, Wout, wcat, woutT);
    hipLaunchKernelGGL(ln_proj, dim3(1024), dim3(256), 0, stream,
                       pair, gamma, beta, wcat, qt, kt, vt, gt, bt);
    hipLaunchKernelGGL(attn, dim3(1024), dim3(256), 0, stream,
                       qt, kt, vt, gt, bt, og);
    hipLaunchKernelGGL(out_gemm, dim3(1024), dim3(256), 0, stream,
                       og, woutT, out);
}